// Round 9
// baseline (221.039 us; speedup 1.0000x reference)
//
#include <hip/hip_runtime.h>
#include <math.h>

// Exact IEEE semantics in the visibility path: no fma contraction anywhere.
#pragma clang fp contract(off)

#define IMG_H 128
#define IMG_W 128
#define HW (IMG_H * IMG_W)
#define NB 2
#define NV 1300
#define NF 2500
#define EPSF 1e-8f
#define NREG 64      // 8x8 grid of 16x16 px regions
#define KSL 8        // depth-slab slices per region
#define NBLK (NREG * NB * KSL) // 1024 WGs x 4 waves (one per 8x8 quadrant)

// ws layout (bytes):
//   vn     f32[NB*NV*3]            @ 0        (31200 B)
//   cnt    i32[NB*NREG]            @ 31200    (512 B)
//   face   f4 [4][NB][NF]          @ 31712    (320000 B) SoA: E0|E1|FD|BB
//   bin    u16[NB][NREG][NF]       @ 351712   (640000 B) face-index bins
//   dbuf   u64[KSL][NB][HW]        @ 991712   (2 MB)     per-slice depth|idx
#define OFF_CNT 31200
#define OFF_FACE 31712
#define OFF_BIN 351712
#define OFF_DBUF 991712

#define DINIT 0x7F800000FFFFFFFFull // depth=+inf, fidx=~0

__device__ __forceinline__ float bcastf(float v, int s) {
    return __int_as_float(__builtin_amdgcn_readlane(__float_as_int(v), s));
}

// Transform + face setup + vertex-normal scatter + screen-space binning.
// Binning: conservative region span from the (already margin-padded) bbox,
// widened by +-1e-4 region units; extra entries are harmless (per-pixel
// exact test unchanged), missing entries impossible. Bin capacity = NF so
// overflow cannot occur (each face enters a region at most once).
__global__ __launch_bounds__(256) void k_face(const float* __restrict__ verts,
                                              const int* __restrict__ faces,
                                              float* __restrict__ vn,
                                              float4* __restrict__ face,
                                              int* __restrict__ cnt,
                                              unsigned short* __restrict__ bin) {
    int i = blockIdx.x * 256 + threadIdx.x;
    if (i >= NB * NF) return;
    int b = i / NF;
    int f = i - b * NF;
    int i0 = faces[f * 3 + 0];
    int i1 = faces[f * 3 + 1];
    int i2 = faces[f * 3 + 2];
    const float* wv = verts + (size_t)b * NV * 3;
    // transform, bit-identical to ref: ndc = (12*(-vx))/(2-vz), z = 2-vz
    float v0x = wv[i0 * 3 + 0], v0y = wv[i0 * 3 + 1], v0z = wv[i0 * 3 + 2];
    float v1x = wv[i1 * 3 + 0], v1y = wv[i1 * 3 + 1], v1z = wv[i1 * 3 + 2];
    float v2x = wv[i2 * 3 + 0], v2y = wv[i2 * 3 + 1], v2z = wv[i2 * 3 + 2];
    float z0 = 2.0f - v0z, z1 = 2.0f - v1z, z2 = 2.0f - v2z;
    float p0x = (12.0f * (-v0x)) / z0, p0y = (12.0f * v0y) / z0;
    float p1x = (12.0f * (-v1x)) / z1, p1y = (12.0f * v1y) / z1;
    float p2x = (12.0f * (-v2x)) / z2, p2y = (12.0f * v2y) / z2;

    float t1 = (p1x - p0x) * (p2y - p0y);
    float t2 = (p1y - p0y) * (p2x - p0x);
    float area = t1 - t2;
    float aabs = fabsf(area);
    float area_safe = (aabs < EPSF) ? EPSF : area;
    bool valid = aabs > EPSF;
    float minx, maxx, miny, maxy;
    if (valid) {
        minx = fminf(p0x, fminf(p1x, p2x)) - 1e-3f;
        maxx = fmaxf(p0x, fmaxf(p1x, p2x)) + 1e-3f;
        miny = fminf(p0y, fminf(p1y, p2y)) - 1e-3f;
        maxy = fmaxf(p0y, fmaxf(p1y, p2y)) + 1e-3f;
    } else {
        minx = 1e30f; maxx = -1e30f; miny = 1e30f; maxy = -1e30f;
    }
    // SoA planes: E0 | E1 | FD | BB, each [NB][NF] float4
    int o = b * NF + f;
    face[0 * NB * NF + o] = make_float4(p2x - p1x, p2y - p1y, p1x, p1y);
    face[1 * NB * NF + o] = make_float4(p0x - p2x, p0y - p2y, p2x, p2y);
    face[2 * NB * NF + o] = make_float4(area_safe, z0, z1, z2);
    face[3 * NB * NF + o] = make_float4(minx, maxx, miny, maxy);

    // world-space face normal -> scatter to vertex normals
    float ax = v1x - v0x, ay = v1y - v0y, az = v1z - v0z;
    float bx = v2x - v0x, by = v2y - v0y, bz = v2z - v0z;
    float fnx = ay * bz - az * by;
    float fny = az * bx - ax * bz;
    float fnz = ax * by - ay * bx;
    float* vnb = vn + (size_t)b * NV * 3;
    atomicAdd(&vnb[i0 * 3 + 0], fnx);
    atomicAdd(&vnb[i0 * 3 + 1], fny);
    atomicAdd(&vnb[i0 * 3 + 2], fnz);
    atomicAdd(&vnb[i1 * 3 + 0], fnx);
    atomicAdd(&vnb[i1 * 3 + 1], fny);
    atomicAdd(&vnb[i1 * 3 + 2], fnz);
    atomicAdd(&vnb[i2 * 3 + 0], fnx);
    atomicAdd(&vnb[i2 * 3 + 1], fny);
    atomicAdd(&vnb[i2 * 3 + 2], fnz);

    if (!valid) return;
    // Region span. Region rx covers cols [16rx,16rx+15]; pixel-center x
    // interval [1-(32rx+31)/128, 1-(32rx+1)/128]. Intersect with
    // [minx,maxx], widened conservatively.
    float rxmin_f = (128.0f * (1.0f - maxx) - 31.0f) / 32.0f;
    float rxmax_f = (128.0f * (1.0f - minx) - 1.0f) / 32.0f;
    float rymin_f = (128.0f * (1.0f - maxy) - 31.0f) / 32.0f;
    float rymax_f = (128.0f * (1.0f - miny) - 1.0f) / 32.0f;
    rxmin_f = fminf(fmaxf(rxmin_f, -1.0f), 8.0f);
    rxmax_f = fminf(fmaxf(rxmax_f, -1.0f), 8.0f);
    rymin_f = fminf(fmaxf(rymin_f, -1.0f), 8.0f);
    rymax_f = fminf(fmaxf(rymax_f, -1.0f), 8.0f);
    int rx0 = (int)ceilf(rxmin_f - 1e-4f); if (rx0 < 0) rx0 = 0;
    int rx1 = (int)floorf(rxmax_f + 1e-4f); if (rx1 > 7) rx1 = 7;
    int ry0 = (int)ceilf(rymin_f - 1e-4f); if (ry0 < 0) ry0 = 0;
    int ry1 = (int)floorf(rymax_f + 1e-4f); if (ry1 > 7) ry1 = 7;
    for (int ry = ry0; ry <= ry1; ++ry) {
        for (int rx = rx0; rx <= rx1; ++rx) {
            int reg = ry * 8 + rx;
            int pos = atomicAdd(&cnt[b * NREG + reg], 1);
            bin[((size_t)b * NREG + reg) * NF + pos] = (unsigned short)f;
        }
    }
}

// WG = (region, batch, slice k) = 256 threads = 4 independent waves, one per
// 8x8 quadrant of the 16x16 region. Each wave scans slice k of the region's
// bin (u16 indices, coalesced), gathers the face records (L2-resident SoA),
// applies the proven bbox + conservative corner cull, readlane-redistributes
// survivors, runs the bit-exact per-pixel path, one coalesced slab store.
// Face-visits: ~190k total vs 1.29M for the chunk-scan design (7x fewer).
__global__ __launch_bounds__(256) void k_raster(const float4* __restrict__ face,
                                                const int* __restrict__ cnt,
                                                const unsigned short* __restrict__ bin,
                                                unsigned long long* __restrict__ dbuf) {
    int t = threadIdx.x;
    int wid = t >> 6, lid = t & 63;
    int bx = blockIdx.x;

    int k = bx & (KSL - 1);
    int b = (bx >> 3) & 1;
    int reg = bx >> 4;         // 0..63
    int r0 = (reg >> 3) * 16;  // 8 row-bands of 16 px
    int c0 = (reg & 7) * 16;   // 8 col-bands of 16 px
    int r0w = r0 + (wid >> 1) * 8;
    int c0w = c0 + (wid & 1) * 8;

    int n = cnt[b * NREG + reg];
    int len = (n + KSL - 1) / KSL;
    int start = k * len; if (start > n) start = n;
    int end = start + len; if (end > n) end = n;

    // wave-tile pixel-center box; px(c) = 1-(2c+1)/128, decreasing in c.
    float txhi = 1.0f - (2.0f * (float)c0w + 1.0f) / 128.0f;
    float txlo = 1.0f - (2.0f * (float)(c0w + 7) + 1.0f) / 128.0f;
    float tyhi = 1.0f - (2.0f * (float)r0w + 1.0f) / 128.0f;
    float tylo = 1.0f - (2.0f * (float)(r0w + 7) + 1.0f) / 128.0f;

    const float4* pE0 = face + (size_t)(0 * NB + b) * NF;
    const float4* pE1 = face + (size_t)(1 * NB + b) * NF;
    const float4* pFD = face + (size_t)(2 * NB + b) * NF;
    const float4* pBB = face + (size_t)(3 * NB + b) * NF;
    const unsigned short* pbin = bin + ((size_t)b * NREG + reg) * NF;

    int r = r0w + (lid >> 3);
    int c = c0w + (lid & 7);
    int p = r * IMG_W + c;
    float px = 1.0f - (2.0f * (float)c + 1.0f) / 128.0f;
    float py = 1.0f - (2.0f * (float)r + 1.0f) / 128.0f;

    unsigned long long best = DINIT;

    for (int base = start; base < end; base += 64) {
        int ii = base + lid;
        int jj = (ii < end) ? ii : (end - 1); // safe: end > base here
        int fi = (int)pbin[jj];
        float4 bb = pBB[fi]; // gathered {minx, maxx, miny, maxy}
        bool pass = false;
        float4 E0, E1, FD;
        if (ii < end) {
            pass = (bb.y >= txlo) && (bb.x <= txhi) && (bb.w >= tylo) && (bb.z <= tyhi);
            if (pass) {
                E0 = pE0[fi];
                E1 = pE1[fi];
                FD = pFD[fi];
                float as = FD.x;
                // Bound each affine edge fn over the tile rect via corner
                // products; all-corners-outside (with DL >> FP rounding of
                // the per-pixel edge expr ~2e-7) => no pixel center passes.
                float u0l = E0.x * (tylo - E0.w), u0h = E0.x * (tyhi - E0.w);
                float u0mn = fminf(u0l, u0h), u0mx = fmaxf(u0l, u0h);
                float u1l = E1.x * (tylo - E1.w), u1h = E1.x * (tyhi - E1.w);
                float u1mn = fminf(u1l, u1h), u1mx = fmaxf(u1l, u1h);
                float v0l = E0.y * (txlo - E0.z), v0h = E0.y * (txhi - E0.z);
                float v0mn = fminf(v0l, v0h), v0mx = fmaxf(v0l, v0h);
                float v1l = E1.y * (txlo - E1.z), v1h = E1.y * (txhi - E1.z);
                float v1mn = fminf(v1l, v1h), v1mx = fmaxf(v1l, v1h);
                float e0mx = u0mx - v0mn, e0mn = u0mn - v0mx;
                float e1mx = u1mx - v1mn, e1mn = u1mn - v1mx;
                const float DL = 1e-4f;
                if (as > 0.0f) {
                    pass = (e0mx >= -DL) && (e1mx >= -DL) && (((as - e0mn) - e1mn) >= -DL);
                } else {
                    pass = (e0mn <= DL) && (e1mn <= DL) && (((as - e0mx) - e1mx) <= DL);
                }
            }
        }
        unsigned long long m = __ballot(pass);
        while (m) {
            int s = (int)__builtin_ctzll(m);
            m &= m - 1;
            // broadcast candidate's bbox from lane s (readlane ignores exec)
            float bmnx = bcastf(bb.x, s), bmxx = bcastf(bb.y, s);
            float bmny = bcastf(bb.z, s), bmxy = bcastf(bb.w, s);
            if (px >= bmnx && px <= bmxx && py >= bmny && py <= bmxy) {
                float e0x = bcastf(E0.x, s), e0y = bcastf(E0.y, s);
                float e0z = bcastf(E0.z, s), e0w = bcastf(E0.w, s);
                float e1x = bcastf(E1.x, s), e1y = bcastf(E1.y, s);
                float e1z = bcastf(E1.z, s), e1w = bcastf(E1.w, s);
                float as  = bcastf(FD.x, s), fz0 = bcastf(FD.y, s);
                float fz1 = bcastf(FD.z, s), fz2 = bcastf(FD.w, s);
                int fcand = __builtin_amdgcn_readlane(fi, s);
                // exact ref order: e = (bx-ax)*(py-ay) - (by-ay)*(px-ax)
                float u1 = e0x * (py - e0w);
                float u2 = e0y * (px - e0z);
                float e0 = u1 - u2;
                float u3 = e1x * (py - e1w);
                float u4 = e1y * (px - e1z);
                float e1 = u3 - u4;
                bool ok = (as > 0.0f) ? (e0 >= 0.0f && e1 >= 0.0f)
                                      : (e0 <= 0.0f && e1 <= 0.0f);
                if (ok) {
                    float b0 = e0 / as; // true IEEE division, as in ref
                    float b1 = e1 / as;
                    float b2 = (1.0f - b0) - b1;
                    if (b2 >= 0.0f) {
                        float S = ((b0 / fz0) + (b1 / fz1)) + (b2 / fz2);
                        if (S > EPSF) {
                            float depth = 1.0f / fmaxf(S, EPSF);
                            unsigned long long pk =
                                ((unsigned long long)__float_as_uint(depth) << 32) |
                                (unsigned)fcand;
                            if (pk < best) best = pk;
                        }
                    }
                }
            }
        }
    }
    dbuf[((size_t)k * NB + b) * HW + p] = best;
}

__global__ __launch_bounds__(256) void k_shade(const float* __restrict__ verts,
                                               const int* __restrict__ faces,
                                               const float* __restrict__ vn,
                                               const unsigned long long* __restrict__ dbuf,
                                               float* __restrict__ out) {
    int i = blockIdx.x * 256 + threadIdx.x; // 0..NB*HW-1
    int b = i >> 14;
    int p = i & (HW - 1);
    unsigned long long pk = DINIT;
    for (int k = 0; k < KSL; ++k) {
        unsigned long long v = dbuf[((size_t)k * NB + b) * HW + p];
        if (v < pk) pk = v;
    }
    unsigned dbits = (unsigned)(pk >> 32);
    bool hit = dbits < 0x7F800000u;
    float cr = 255.0f, cg = 255.0f, cb = 255.0f, alpha = 0.0f;
    if (hit) {
        alpha = 1.0f;
        int f = (int)(unsigned)(pk & 0xFFFFFFFFull);
        int row = p >> 7;
        int col = p & 127;
        float px = 1.0f - (2.0f * (float)col + 1.0f) / 128.0f;
        float py = 1.0f - (2.0f * (float)row + 1.0f) / 128.0f;
        int i0 = faces[f * 3 + 0];
        int i1 = faces[f * 3 + 1];
        int i2 = faces[f * 3 + 2];
        const float* wv = verts + (size_t)b * NV * 3;
        float v0x = wv[i0 * 3 + 0], v0y = wv[i0 * 3 + 1], v0z = wv[i0 * 3 + 2];
        float v1x = wv[i1 * 3 + 0], v1y = wv[i1 * 3 + 1], v1z = wv[i1 * 3 + 2];
        float v2x = wv[i2 * 3 + 0], v2y = wv[i2 * 3 + 1], v2z = wv[i2 * 3 + 2];
        // transform, bit-identical to k_face/ref
        float z0 = 2.0f - v0z, z1 = 2.0f - v1z, z2 = 2.0f - v2z;
        float a0x = (12.0f * (-v0x)) / z0, a0y = (12.0f * v0y) / z0;
        float a1x = (12.0f * (-v1x)) / z1, a1y = (12.0f * v1y) / z1;
        float a2x = (12.0f * (-v2x)) / z2, a2y = (12.0f * v2y) / z2;

        float t1 = (a1x - a0x) * (a2y - a0y);
        float t2 = (a1y - a0y) * (a2x - a0x);
        float ar = t1 - t2;
        ar = (fabsf(ar) < EPSF) ? EPSF : ar;
        float u1 = (a2x - a1x) * (py - a1y);
        float u2 = (a2y - a1y) * (px - a1x);
        float bb0 = (u1 - u2) / ar;
        float u3 = (a0x - a2x) * (py - a2y);
        float u4 = (a0y - a2y) * (px - a2x);
        float bb1 = (u3 - u4) / ar;
        float bb2 = (1.0f - bb0) - bb1;
        float w0 = bb0 / z0;
        float w1 = bb1 / z1;
        float w2 = bb2 / z2;
        float denom = ((w0 + w1) + w2) + EPSF;
        float pc0 = w0 / denom;
        float pc1 = w1 / denom;
        float pc2 = w2 / denom;

        float posx = (pc0 * v0x + pc1 * v1x) + pc2 * v2x;
        float posy = (pc0 * v0y + pc1 * v1y) + pc2 * v2y;
        float posz = (pc0 * v0z + pc1 * v1z) + pc2 * v2z;

        const float* vnb = vn + (size_t)b * NV * 3;
        float n0x = vnb[i0 * 3 + 0], n0y = vnb[i0 * 3 + 1], n0z = vnb[i0 * 3 + 2];
        float n1x = vnb[i1 * 3 + 0], n1y = vnb[i1 * 3 + 1], n1z = vnb[i1 * 3 + 2];
        float n2x = vnb[i2 * 3 + 0], n2y = vnb[i2 * 3 + 1], n2z = vnb[i2 * 3 + 2];
        float in0 = 1.0f / (sqrtf(n0x * n0x + n0y * n0y + n0z * n0z) + EPSF);
        float in1 = 1.0f / (sqrtf(n1x * n1x + n1y * n1y + n1z * n1z) + EPSF);
        float in2 = 1.0f / (sqrtf(n2x * n2x + n2y * n2y + n2z * n2z) + EPSF);
        n0x *= in0; n0y *= in0; n0z *= in0;
        n1x *= in1; n1y *= in1; n1z *= in1;
        n2x *= in2; n2y *= in2; n2z *= in2;
        float nx = (pc0 * n0x + pc1 * n1x) + pc2 * n2x;
        float ny = (pc0 * n0y + pc1 * n1y) + pc2 * n2y;
        float nz = (pc0 * n0z + pc1 * n1z) + pc2 * n2z;
        float inn = 1.0f / (sqrtf(nx * nx + ny * ny + nz * nz) + EPSF);
        nx *= inn; ny *= inn; nz *= inn;

        float lx = 0.0f - posx, ly = 1.0f - posy, lz = 3.0f - posz;
        float iln = 1.0f / (sqrtf(lx * lx + ly * ly + lz * lz) + EPSF);
        lx *= iln; ly *= iln; lz *= iln;
        float vx = 0.0f - posx, vy = 0.0f - posy, vz = 2.0f - posz;
        float ivn = 1.0f / (sqrtf(vx * vx + vy * vy + vz * vz) + EPSF);
        vx *= ivn; vy *= ivn; vz *= ivn;

        float ndl = nx * lx + ny * ly + nz * lz;
        float ndlr = fmaxf(ndl, 0.0f);
        float rx = 2.0f * ndl * nx - lx;
        float ry = 2.0f * ndl * ny - ly;
        float rz = 2.0f * ndl * nz - lz;
        float sc = fmaxf(rx * vx + ry * vy + rz * vz, 0.0f);
        float spec = 0.2f * 0.6f * powf(sc, 10.0f);
        float shade = 0.5f * 1.0f + 0.3f * 1.0f * ndlr;
        cr = ((142.0f / 255.0f) * shade + spec) * 255.0f;
        cg = ((179.0f / 255.0f) * shade + spec) * 255.0f;
        cb = ((247.0f / 255.0f) * shade + spec) * 255.0f;
    }
    float* img = out + (size_t)b * 3 * HW;
    img[0 * HW + p] = cr;
    img[1 * HW + p] = cg;
    img[2 * HW + p] = cb;
    out[(size_t)NB * 3 * HW + (size_t)b * HW + p] = alpha;
}

extern "C" void kernel_launch(void* const* d_in, const int* in_sizes, int n_in,
                              void* d_out, int out_size, void* d_ws, size_t ws_size,
                              hipStream_t stream) {
    const float* verts = (const float*)d_in[0]; // [NB, NV, 3]
    const int* faces = (const int*)d_in[1];     // [NF, 3]
    char* ws = (char*)d_ws;
    float* vn = (float*)(ws + 0);
    int* cnt = (int*)(ws + OFF_CNT);
    float4* face = (float4*)(ws + OFF_FACE);
    unsigned short* bin = (unsigned short*)(ws + OFF_BIN);
    unsigned long long* dbuf = (unsigned long long*)(ws + OFF_DBUF);
    float* out = (float*)d_out;

    // zero vn + bin counters in one contiguous memset
    hipMemsetAsync(ws, 0, OFF_CNT + NB * NREG * sizeof(int), stream);
    k_face<<<(NB * NF + 255) / 256, 256, 0, stream>>>(verts, faces, vn, face, cnt, bin);
    k_raster<<<NBLK, 256, 0, stream>>>(face, cnt, bin, dbuf);
    k_shade<<<(NB * HW) / 256, 256, 0, stream>>>(verts, faces, vn, dbuf, out);
}

// Round 10
// 117.184 us; speedup vs baseline: 1.8862x; 1.8862x over previous
//
#include <hip/hip_runtime.h>
#include <math.h>

// Exact IEEE semantics in the visibility path: no fma contraction anywhere.
#pragma clang fp contract(off)

#define IMG_H 128
#define IMG_W 128
#define HW (IMG_H * IMG_W)
#define NB 2
#define NV 1300
#define NF 2500
#define EPSF 1e-8f
#define NCHUNK 32
#define CHUNK ((NF + NCHUNK - 1) / NCHUNK) // 79
#define NREG 128 // 8x16 grid of 16w x 8h px regions; one WAVE per region now
// wave-tasks: 128 regions x NB x NCHUNK = 8192 (2 px/lane), 4 waves/WG
#define NBLK 2048

// ws layout (bytes):
//   vn     f32[NB*NV*3]          @ 0       (31200 B)
//   face   f4 [4][NB][NF]        @ 31232   (320000 B)  SoA: E0|E1|FD|BB planes
//   dbuf   u64[NCHUNK][NB][HW]   @ 351488  (8 MB)      per-chunk depth|idx slab
#define OFF_FACE 31232
#define OFF_DBUF 351488

#define DINIT 0x7F800000FFFFFFFFull // depth=+inf, fidx=~0

__device__ __forceinline__ float bcastf(float v, int s) {
    return __int_as_float(__builtin_amdgcn_readlane(__float_as_int(v), s));
}

__global__ __launch_bounds__(256) void k_face(const float* __restrict__ verts,
                                              const int* __restrict__ faces,
                                              float* __restrict__ vn,
                                              float4* __restrict__ face) {
    int i = blockIdx.x * 256 + threadIdx.x;
    if (i >= NB * NF) return;
    int b = i / NF;
    int f = i - b * NF;
    int i0 = faces[f * 3 + 0];
    int i1 = faces[f * 3 + 1];
    int i2 = faces[f * 3 + 2];
    const float* wv = verts + (size_t)b * NV * 3;
    // transform, bit-identical to ref: ndc = (12*(-vx))/(2-vz), z = 2-vz
    float v0x = wv[i0 * 3 + 0], v0y = wv[i0 * 3 + 1], v0z = wv[i0 * 3 + 2];
    float v1x = wv[i1 * 3 + 0], v1y = wv[i1 * 3 + 1], v1z = wv[i1 * 3 + 2];
    float v2x = wv[i2 * 3 + 0], v2y = wv[i2 * 3 + 1], v2z = wv[i2 * 3 + 2];
    float z0 = 2.0f - v0z, z1 = 2.0f - v1z, z2 = 2.0f - v2z;
    float p0x = (12.0f * (-v0x)) / z0, p0y = (12.0f * v0y) / z0;
    float p1x = (12.0f * (-v1x)) / z1, p1y = (12.0f * v1y) / z1;
    float p2x = (12.0f * (-v2x)) / z2, p2y = (12.0f * v2y) / z2;

    float t1 = (p1x - p0x) * (p2y - p0y);
    float t2 = (p1y - p0y) * (p2x - p0x);
    float area = t1 - t2;
    float aabs = fabsf(area);
    float area_safe = (aabs < EPSF) ? EPSF : area;
    bool valid = aabs > EPSF;
    float minx, maxx, miny, maxy;
    if (valid) {
        minx = fminf(p0x, fminf(p1x, p2x)) - 1e-3f;
        maxx = fmaxf(p0x, fmaxf(p1x, p2x)) + 1e-3f;
        miny = fminf(p0y, fminf(p1y, p2y)) - 1e-3f;
        maxy = fmaxf(p0y, fmaxf(p1y, p2y)) + 1e-3f;
    } else {
        minx = 1e30f; maxx = -1e30f; miny = 1e30f; maxy = -1e30f;
    }
    // SoA planes: E0 | E1 | FD | BB, each [NB][NF] float4 -> coalesced reads
    int o = b * NF + f;
    face[0 * NB * NF + o] = make_float4(p2x - p1x, p2y - p1y, p1x, p1y);
    face[1 * NB * NF + o] = make_float4(p0x - p2x, p0y - p2y, p2x, p2y);
    face[2 * NB * NF + o] = make_float4(area_safe, z0, z1, z2);
    face[3 * NB * NF + o] = make_float4(minx, maxx, miny, maxy);

    // world-space face normal -> scatter to vertex normals
    float ax = v1x - v0x, ay = v1y - v0y, az = v1z - v0z;
    float bx = v2x - v0x, by = v2y - v0y, bz = v2z - v0z;
    float fnx = ay * bz - az * by;
    float fny = az * bx - ax * bz;
    float fnz = ax * by - ay * bx;
    float* vnb = vn + (size_t)b * NV * 3;
    atomicAdd(&vnb[i0 * 3 + 0], fnx);
    atomicAdd(&vnb[i0 * 3 + 1], fny);
    atomicAdd(&vnb[i0 * 3 + 2], fnz);
    atomicAdd(&vnb[i1 * 3 + 0], fnx);
    atomicAdd(&vnb[i1 * 3 + 1], fny);
    atomicAdd(&vnb[i1 * 3 + 2], fnz);
    atomicAdd(&vnb[i2 * 3 + 0], fnx);
    atomicAdd(&vnb[i2 * 3 + 1], fny);
    atomicAdd(&vnb[i2 * 3 + 2], fnz);
}

// 256-thread WG = 4 CONCURRENT independent waves (zero LDS, zero barriers).
// ONE WAVE PER FULL 16x8 REGION, 2 pixels/lane (rows r and r+4): halves the
// wave count vs the 8x8-tile design at the same balanced task grain, and
// amortizes the per-candidate ballot/broadcast cost over 128 px instead of
// 64. Decode: wave-task = bx*4+wid -> chunk=((bx&7)<<2)|wid, b=(bx>>3)&1,
// reg=bx>>4. The 4 waves of a WG share (b,reg), consecutive chunks -> 20 KB
// WG face working set (L1-resident). Per-candidate: bbox + conservative
// corner cull over the 16x8 tile, readlane redistribute, bit-exact per-pixel
// path run for both pixels, two coalesced slab stores.
__global__ __launch_bounds__(256) void k_raster(const float4* __restrict__ face,
                                                unsigned long long* __restrict__ dbuf) {
    int t = threadIdx.x;
    int wid = t >> 6, lid = t & 63;
    int bx = blockIdx.x;

    int chunk = ((bx & 7) << 2) | wid;  // 0..31
    int b = (bx >> 3) & 1;
    int reg = bx >> 4;        // 0..127
    int r0 = (reg >> 3) * 8;  // 16 row-bands of 8 px
    int c0 = (reg & 7) * 16;  // 8 col-bands of 16 px
    int f0 = chunk * CHUNK;
    int nf = NF - f0; if (nf > CHUNK) nf = CHUNK;

    // region pixel-center box; px(c) = 1-(2c+1)/128, strictly decreasing.
    float txhi = 1.0f - (2.0f * (float)c0 + 1.0f) / 128.0f;
    float txlo = 1.0f - (2.0f * (float)(c0 + 15) + 1.0f) / 128.0f;
    float tyhi = 1.0f - (2.0f * (float)r0 + 1.0f) / 128.0f;
    float tylo = 1.0f - (2.0f * (float)(r0 + 7) + 1.0f) / 128.0f;

    const float4* pE0 = face + (size_t)(0 * NB + b) * NF + f0;
    const float4* pE1 = face + (size_t)(1 * NB + b) * NF + f0;
    const float4* pFD = face + (size_t)(2 * NB + b) * NF + f0;
    const float4* pBB = face + (size_t)(3 * NB + b) * NF + f0;

    // 2 px/lane: col = c0+(lid&15), rows r0+(lid>>4) and r0+(lid>>4)+4
    int c = c0 + (lid & 15);
    int ra = r0 + (lid >> 4);
    int rb = ra + 4;
    int pa = ra * IMG_W + c;
    int pb = rb * IMG_W + c;
    float px = 1.0f - (2.0f * (float)c + 1.0f) / 128.0f;
    float pya = 1.0f - (2.0f * (float)ra + 1.0f) / 128.0f;
    float pyb = 1.0f - (2.0f * (float)rb + 1.0f) / 128.0f;

    unsigned long long besta = DINIT;
    unsigned long long bestb = DINIT;

    for (int base = 0; base < nf; base += 64) {
        int tt = base + lid;
        int fi = (tt < nf) ? tt : (nf - 1); // clamp: loads stay in-bounds
        float4 bb = pBB[fi]; // {minx, maxx, miny, maxy}
        float4 E0 = pE0[fi];
        float4 E1 = pE1[fi];
        float4 FD = pFD[fi];
        bool pass = false;
        if (tt < nf) {
            pass = (bb.y >= txlo) && (bb.x <= txhi) && (bb.w >= tylo) && (bb.z <= tyhi);
            if (pass) {
                float as = FD.x;
                // Bound each affine edge fn over the tile rect via corner
                // products; all-corners-outside (with DL >> FP rounding of
                // the per-pixel edge expr ~2e-7) => no pixel center passes.
                float u0l = E0.x * (tylo - E0.w), u0h = E0.x * (tyhi - E0.w);
                float u0mn = fminf(u0l, u0h), u0mx = fmaxf(u0l, u0h);
                float u1l = E1.x * (tylo - E1.w), u1h = E1.x * (tyhi - E1.w);
                float u1mn = fminf(u1l, u1h), u1mx = fmaxf(u1l, u1h);
                float v0l = E0.y * (txlo - E0.z), v0h = E0.y * (txhi - E0.z);
                float v0mn = fminf(v0l, v0h), v0mx = fmaxf(v0l, v0h);
                float v1l = E1.y * (txlo - E1.z), v1h = E1.y * (txhi - E1.z);
                float v1mn = fminf(v1l, v1h), v1mx = fmaxf(v1l, v1h);
                float e0mx = u0mx - v0mn, e0mn = u0mn - v0mx;
                float e1mx = u1mx - v1mn, e1mn = u1mn - v1mx;
                const float DL = 1e-4f;
                if (as > 0.0f) {
                    pass = (e0mx >= -DL) && (e1mx >= -DL) && (((as - e0mn) - e1mn) >= -DL);
                } else {
                    pass = (e0mn <= DL) && (e1mn <= DL) && (((as - e0mx) - e1mx) <= DL);
                }
            }
        }
        unsigned long long m = __ballot(pass);
        while (m) {
            int s = (int)__builtin_ctzll(m);
            m &= m - 1;
            // broadcast candidate from lane s (readlane ignores exec)
            float bmnx = bcastf(bb.x, s), bmxx = bcastf(bb.y, s);
            float bmny = bcastf(bb.z, s), bmxy = bcastf(bb.w, s);
            bool inx = (px >= bmnx) && (px <= bmxx);
            bool ina = inx && (pya >= bmny) && (pya <= bmxy);
            bool inb = inx && (pyb >= bmny) && (pyb <= bmxy);
            if (ina || inb) {
                float e0x = bcastf(E0.x, s), e0y = bcastf(E0.y, s);
                float e0z = bcastf(E0.z, s), e0w = bcastf(E0.w, s);
                float e1x = bcastf(E1.x, s), e1y = bcastf(E1.y, s);
                float e1z = bcastf(E1.z, s), e1w = bcastf(E1.w, s);
                float as  = bcastf(FD.x, s), fz0 = bcastf(FD.y, s);
                float fz1 = bcastf(FD.z, s), fz2 = bcastf(FD.w, s);
                unsigned fidx = (unsigned)(f0 + base + s);
                float u2 = e0y * (px - e0z); // x-terms shared by both pixels
                float u4 = e1y * (px - e1z);
                if (ina) {
                    // exact ref order: e = (bx-ax)*(py-ay) - (by-ay)*(px-ax)
                    float u1 = e0x * (pya - e0w);
                    float e0 = u1 - u2;
                    float u3 = e1x * (pya - e1w);
                    float e1 = u3 - u4;
                    bool ok = (as > 0.0f) ? (e0 >= 0.0f && e1 >= 0.0f)
                                          : (e0 <= 0.0f && e1 <= 0.0f);
                    if (ok) {
                        float b0 = e0 / as; // true IEEE division, as in ref
                        float b1 = e1 / as;
                        float b2 = (1.0f - b0) - b1;
                        if (b2 >= 0.0f) {
                            float S = ((b0 / fz0) + (b1 / fz1)) + (b2 / fz2);
                            if (S > EPSF) {
                                float depth = 1.0f / fmaxf(S, EPSF);
                                unsigned long long pk =
                                    ((unsigned long long)__float_as_uint(depth) << 32) | fidx;
                                if (pk < besta) besta = pk;
                            }
                        }
                    }
                }
                if (inb) {
                    float u1 = e0x * (pyb - e0w);
                    float e0 = u1 - u2;
                    float u3 = e1x * (pyb - e1w);
                    float e1 = u3 - u4;
                    bool ok = (as > 0.0f) ? (e0 >= 0.0f && e1 >= 0.0f)
                                          : (e0 <= 0.0f && e1 <= 0.0f);
                    if (ok) {
                        float b0 = e0 / as;
                        float b1 = e1 / as;
                        float b2 = (1.0f - b0) - b1;
                        if (b2 >= 0.0f) {
                            float S = ((b0 / fz0) + (b1 / fz1)) + (b2 / fz2);
                            if (S > EPSF) {
                                float depth = 1.0f / fmaxf(S, EPSF);
                                unsigned long long pk =
                                    ((unsigned long long)__float_as_uint(depth) << 32) | fidx;
                                if (pk < bestb) bestb = pk;
                            }
                        }
                    }
                }
            }
        }
    }
    unsigned long long* dslab = dbuf + ((size_t)chunk * NB + b) * HW;
    dslab[pa] = besta;
    dslab[pb] = bestb;
}

__global__ __launch_bounds__(256) void k_shade(const float* __restrict__ verts,
                                               const int* __restrict__ faces,
                                               const float* __restrict__ vn,
                                               const unsigned long long* __restrict__ dbuf,
                                               float* __restrict__ out) {
    int i = blockIdx.x * 256 + threadIdx.x; // 0..NB*HW-1
    int b = i >> 14;
    int p = i & (HW - 1);
    unsigned long long pk = DINIT;
    for (int k = 0; k < NCHUNK; ++k) {
        unsigned long long v = dbuf[((size_t)k * NB + b) * HW + p];
        if (v < pk) pk = v;
    }
    unsigned dbits = (unsigned)(pk >> 32);
    bool hit = dbits < 0x7F800000u;
    float cr = 255.0f, cg = 255.0f, cb = 255.0f, alpha = 0.0f;
    if (hit) {
        alpha = 1.0f;
        int f = (int)(unsigned)(pk & 0xFFFFFFFFull);
        int row = p >> 7;
        int col = p & 127;
        float px = 1.0f - (2.0f * (float)col + 1.0f) / 128.0f;
        float py = 1.0f - (2.0f * (float)row + 1.0f) / 128.0f;
        int i0 = faces[f * 3 + 0];
        int i1 = faces[f * 3 + 1];
        int i2 = faces[f * 3 + 2];
        const float* wv = verts + (size_t)b * NV * 3;
        float v0x = wv[i0 * 3 + 0], v0y = wv[i0 * 3 + 1], v0z = wv[i0 * 3 + 2];
        float v1x = wv[i1 * 3 + 0], v1y = wv[i1 * 3 + 1], v1z = wv[i1 * 3 + 2];
        float v2x = wv[i2 * 3 + 0], v2y = wv[i2 * 3 + 1], v2z = wv[i2 * 3 + 2];
        // transform, bit-identical to k_face/ref
        float z0 = 2.0f - v0z, z1 = 2.0f - v1z, z2 = 2.0f - v2z;
        float a0x = (12.0f * (-v0x)) / z0, a0y = (12.0f * v0y) / z0;
        float a1x = (12.0f * (-v1x)) / z1, a1y = (12.0f * v1y) / z1;
        float a2x = (12.0f * (-v2x)) / z2, a2y = (12.0f * v2y) / z2;

        float t1 = (a1x - a0x) * (a2y - a0y);
        float t2 = (a1y - a0y) * (a2x - a0x);
        float ar = t1 - t2;
        ar = (fabsf(ar) < EPSF) ? EPSF : ar;
        float u1 = (a2x - a1x) * (py - a1y);
        float u2 = (a2y - a1y) * (px - a1x);
        float bb0 = (u1 - u2) / ar;
        float u3 = (a0x - a2x) * (py - a2y);
        float u4 = (a0y - a2y) * (px - a2x);
        float bb1 = (u3 - u4) / ar;
        float bb2 = (1.0f - bb0) - bb1;
        float w0 = bb0 / z0;
        float w1 = bb1 / z1;
        float w2 = bb2 / z2;
        float denom = ((w0 + w1) + w2) + EPSF;
        float pc0 = w0 / denom;
        float pc1 = w1 / denom;
        float pc2 = w2 / denom;

        float posx = (pc0 * v0x + pc1 * v1x) + pc2 * v2x;
        float posy = (pc0 * v0y + pc1 * v1y) + pc2 * v2y;
        float posz = (pc0 * v0z + pc1 * v1z) + pc2 * v2z;

        const float* vnb = vn + (size_t)b * NV * 3;
        float n0x = vnb[i0 * 3 + 0], n0y = vnb[i0 * 3 + 1], n0z = vnb[i0 * 3 + 2];
        float n1x = vnb[i1 * 3 + 0], n1y = vnb[i1 * 3 + 1], n1z = vnb[i1 * 3 + 2];
        float n2x = vnb[i2 * 3 + 0], n2y = vnb[i2 * 3 + 1], n2z = vnb[i2 * 3 + 2];
        float in0 = 1.0f / (sqrtf(n0x * n0x + n0y * n0y + n0z * n0z) + EPSF);
        float in1 = 1.0f / (sqrtf(n1x * n1x + n1y * n1y + n1z * n1z) + EPSF);
        float in2 = 1.0f / (sqrtf(n2x * n2x + n2y * n2y + n2z * n2z) + EPSF);
        n0x *= in0; n0y *= in0; n0z *= in0;
        n1x *= in1; n1y *= in1; n1z *= in1;
        n2x *= in2; n2y *= in2; n2z *= in2;
        float nx = (pc0 * n0x + pc1 * n1x) + pc2 * n2x;
        float ny = (pc0 * n0y + pc1 * n1y) + pc2 * n2y;
        float nz = (pc0 * n0z + pc1 * n1z) + pc2 * n2z;
        float inn = 1.0f / (sqrtf(nx * nx + ny * ny + nz * nz) + EPSF);
        nx *= inn; ny *= inn; nz *= inn;

        float lx = 0.0f - posx, ly = 1.0f - posy, lz = 3.0f - posz;
        float iln = 1.0f / (sqrtf(lx * lx + ly * ly + lz * lz) + EPSF);
        lx *= iln; ly *= iln; lz *= iln;
        float vx = 0.0f - posx, vy = 0.0f - posy, vz = 2.0f - posz;
        float ivn = 1.0f / (sqrtf(vx * vx + vy * vy + vz * vz) + EPSF);
        vx *= ivn; vy *= ivn; vz *= ivn;

        float ndl = nx * lx + ny * ly + nz * lz;
        float ndlr = fmaxf(ndl, 0.0f);
        float rx = 2.0f * ndl * nx - lx;
        float ry = 2.0f * ndl * ny - ly;
        float rz = 2.0f * ndl * nz - lz;
        float sc = fmaxf(rx * vx + ry * vy + rz * vz, 0.0f);
        float spec = 0.2f * 0.6f * powf(sc, 10.0f);
        float shade = 0.5f * 1.0f + 0.3f * 1.0f * ndlr;
        cr = ((142.0f / 255.0f) * shade + spec) * 255.0f;
        cg = ((179.0f / 255.0f) * shade + spec) * 255.0f;
        cb = ((247.0f / 255.0f) * shade + spec) * 255.0f;
    }
    float* img = out + (size_t)b * 3 * HW;
    img[0 * HW + p] = cr;
    img[1 * HW + p] = cg;
    img[2 * HW + p] = cb;
    out[(size_t)NB * 3 * HW + (size_t)b * HW + p] = alpha;
}

extern "C" void kernel_launch(void* const* d_in, const int* in_sizes, int n_in,
                              void* d_out, int out_size, void* d_ws, size_t ws_size,
                              hipStream_t stream) {
    const float* verts = (const float*)d_in[0]; // [NB, NV, 3]
    const int* faces = (const int*)d_in[1];     // [NF, 3]
    char* ws = (char*)d_ws;
    float* vn = (float*)(ws + 0);
    float4* face = (float4*)(ws + OFF_FACE);
    unsigned long long* dbuf = (unsigned long long*)(ws + OFF_DBUF);
    float* out = (float*)d_out;

    hipMemsetAsync(vn, 0, NB * NV * 3 * sizeof(float), stream);
    k_face<<<(NB * NF + 255) / 256, 256, 0, stream>>>(verts, faces, vn, face);
    k_raster<<<NBLK, 256, 0, stream>>>(face, dbuf);
    k_shade<<<(NB * HW) / 256, 256, 0, stream>>>(verts, faces, vn, dbuf, out);
}

// Round 11
// 103.181 us; speedup vs baseline: 2.1422x; 1.1357x over previous
//
#include <hip/hip_runtime.h>
#include <math.h>

// Exact IEEE semantics in the visibility path: no fma contraction anywhere.
#pragma clang fp contract(off)

#define IMG_H 128
#define IMG_W 128
#define HW (IMG_H * IMG_W)
#define NB 2
#define NV 1300
#define NF 2500
#define EPSF 1e-8f
#define NCHUNK 32
#define CHUNK ((NF + NCHUNK - 1) / NCHUNK) // 79
#define NREG 128                            // 8x16 grid of 16w x 8h px regions
#define NBLK (NREG * NB * NCHUNK)           // 8192

// ws layout (bytes):
//   vn     f32[NB*NV*3]          @ 0       (31200 B)
//   face   f4 [NB*NF*4]          @ 31232   (320000 B)
//   dbuf   u64[NCHUNK][NB][HW]   @ 351488  (8 MB)     per-chunk depth|idx
#define OFF_FACE 31232
#define OFF_DBUF 351488

#define DINIT 0x7F800000FFFFFFFFull // depth=+inf, fidx=~0

__global__ __launch_bounds__(256) void k_face(const float* __restrict__ verts,
                                              const int* __restrict__ faces,
                                              float* __restrict__ vn,
                                              float4* __restrict__ face) {
    int i = blockIdx.x * 256 + threadIdx.x;
    if (i >= NB * NF) return;
    int b = i / NF;
    int f = i - b * NF;
    int i0 = faces[f * 3 + 0];
    int i1 = faces[f * 3 + 1];
    int i2 = faces[f * 3 + 2];
    const float* wv = verts + (size_t)b * NV * 3;
    // transform, bit-identical to ref: ndc = (12*(-vx))/(2-vz), z = 2-vz
    float v0x = wv[i0 * 3 + 0], v0y = wv[i0 * 3 + 1], v0z = wv[i0 * 3 + 2];
    float v1x = wv[i1 * 3 + 0], v1y = wv[i1 * 3 + 1], v1z = wv[i1 * 3 + 2];
    float v2x = wv[i2 * 3 + 0], v2y = wv[i2 * 3 + 1], v2z = wv[i2 * 3 + 2];
    float z0 = 2.0f - v0z, z1 = 2.0f - v1z, z2 = 2.0f - v2z;
    float p0x = (12.0f * (-v0x)) / z0, p0y = (12.0f * v0y) / z0;
    float p1x = (12.0f * (-v1x)) / z1, p1y = (12.0f * v1y) / z1;
    float p2x = (12.0f * (-v2x)) / z2, p2y = (12.0f * v2y) / z2;

    float t1 = (p1x - p0x) * (p2y - p0y);
    float t2 = (p1y - p0y) * (p2x - p0x);
    float area = t1 - t2;
    float aabs = fabsf(area);
    float area_safe = (aabs < EPSF) ? EPSF : area;
    bool valid = aabs > EPSF;
    float minx, maxx, miny, maxy;
    if (valid) {
        minx = fminf(p0x, fminf(p1x, p2x)) - 1e-3f;
        maxx = fmaxf(p0x, fmaxf(p1x, p2x)) + 1e-3f;
        miny = fminf(p0y, fminf(p1y, p2y)) - 1e-3f;
        maxy = fmaxf(p0y, fmaxf(p1y, p2y)) + 1e-3f;
    } else {
        minx = 1e30f; maxx = -1e30f; miny = 1e30f; maxy = -1e30f;
    }
    int o = (b * NF + f) * 4;
    face[o + 0] = make_float4(p2x - p1x, p2y - p1y, p1x, p1y);
    face[o + 1] = make_float4(p0x - p2x, p0y - p2y, p2x, p2y);
    face[o + 2] = make_float4(area_safe, z0, z1, z2);
    face[o + 3] = make_float4(minx, maxx, miny, maxy);

    // world-space face normal -> scatter to vertex normals
    float ax = v1x - v0x, ay = v1y - v0y, az = v1z - v0z;
    float bx = v2x - v0x, by = v2y - v0y, bz = v2z - v0z;
    float fnx = ay * bz - az * by;
    float fny = az * bx - ax * bz;
    float fnz = ax * by - ay * bx;
    float* vnb = vn + (size_t)b * NV * 3;
    atomicAdd(&vnb[i0 * 3 + 0], fnx);
    atomicAdd(&vnb[i0 * 3 + 1], fny);
    atomicAdd(&vnb[i0 * 3 + 2], fnz);
    atomicAdd(&vnb[i1 * 3 + 0], fnx);
    atomicAdd(&vnb[i1 * 3 + 1], fny);
    atomicAdd(&vnb[i1 * 3 + 2], fnz);
    atomicAdd(&vnb[i2 * 3 + 0], fnx);
    atomicAdd(&vnb[i2 * 3 + 1], fny);
    atomicAdd(&vnb[i2 * 3 + 2], fnz);
}

// Block = 128 threads = 2 waves, covering a 16w x 8h px region (each wave an
// 8x8 quadrant). This is the session-best raster body (41.0 us measured):
// Phase 1: threads 0..CHUNK-1 ballot-test the chunk's face bboxes vs the
// region rect, order-preserving compact into LDS. Phase 2: waves scan.
// (Tile corner-cull removed: measured net loss — costs ~30 VALU inst on all
// 1.29M visits to save only the short bbox-fail path on ~20% of them.)
__global__ __launch_bounds__(128) void k_raster(const float4* __restrict__ face,
                                                unsigned long long* __restrict__ dbuf) {
    __shared__ float4 sface[CHUNK * 4];
    __shared__ int sidx[CHUNK];
    __shared__ int swbase[2];
    __shared__ int scnt;

    int bx = blockIdx.x;
    int chunk = bx & (NCHUNK - 1);
    int tmp = bx >> 5;
    int b = tmp & 1;
    int reg = tmp >> 1;       // 0..127
    int r0 = (reg >> 3) * 8;  // 16 row-bands of 8 px
    int c0 = (reg & 7) * 16;  // 8 col-bands of 16 px
    int f0 = chunk * CHUNK;
    int nf = NF - f0; if (nf > CHUNK) nf = CHUNK;

    float txmax = 1.0f - (2.0f * (float)c0 + 1.0f) / 128.0f;
    float txmin = 1.0f - (2.0f * (float)(c0 + 15) + 1.0f) / 128.0f;
    float tymax = 1.0f - (2.0f * (float)r0 + 1.0f) / 128.0f;
    float tymin = 1.0f - (2.0f * (float)(r0 + 7) + 1.0f) / 128.0f;

    const float4* fb = face + (size_t)b * NF * 4;
    int t = threadIdx.x;
    int wid = t >> 6, lid = t & 63;
    bool pass = false;
    float4 bb;
    if (t < nf) {
        bb = fb[(f0 + t) * 4 + 3]; // {minx, maxx, miny, maxy}
        pass = (bb.y >= txmin) && (bb.x <= txmax) && (bb.w >= tymin) && (bb.z <= tymax);
    }
    unsigned long long m = __ballot(pass);
    if (lid == 0) swbase[wid] = __popcll(m);
    __syncthreads();
    int base0 = swbase[0];
    if (pass) {
        int pos = (wid ? base0 : 0) + __popcll(m & ((1ull << lid) - 1ull));
        sface[pos * 4 + 0] = fb[(f0 + t) * 4 + 0];
        sface[pos * 4 + 1] = fb[(f0 + t) * 4 + 1];
        sface[pos * 4 + 2] = fb[(f0 + t) * 4 + 2];
        sface[pos * 4 + 3] = bb;
        sidx[pos] = f0 + t;
    }
    if (t == 0) scnt = base0 + swbase[1];
    __syncthreads();
    int cnt = scnt;

    int r = r0 + (lid >> 3);
    int c = c0 + wid * 8 + (lid & 7);
    int p = r * IMG_W + c;
    float px = 1.0f - (2.0f * (float)c + 1.0f) / 128.0f;
    float py = 1.0f - (2.0f * (float)r + 1.0f) / 128.0f;

    unsigned long long best = DINIT;
    for (int j = 0; j < cnt; ++j) {
        float4 fbb = sface[j * 4 + 3];
        if (px >= fbb.x && px <= fbb.y && py >= fbb.z && py <= fbb.w) {
            float4 E0 = sface[j * 4 + 0];
            float4 E1 = sface[j * 4 + 1];
            float4 FD = sface[j * 4 + 2];
            // exact ref order: e = (bx-ax)*(py-ay) - (by-ay)*(px-ax)
            float u1 = E0.x * (py - E0.w);
            float u2 = E0.y * (px - E0.z);
            float e0 = u1 - u2;
            float u3 = E1.x * (py - E1.w);
            float u4 = E1.y * (px - E1.z);
            float e1 = u3 - u4;
            float as = FD.x;
            bool ok = (as > 0.0f) ? (e0 >= 0.0f && e1 >= 0.0f)
                                  : (e0 <= 0.0f && e1 <= 0.0f);
            if (ok) {
                float b0 = e0 / as; // true IEEE division, as in ref
                float b1 = e1 / as;
                float b2 = (1.0f - b0) - b1;
                if (b2 >= 0.0f) {
                    float S = ((b0 / FD.y) + (b1 / FD.z)) + (b2 / FD.w);
                    if (S > EPSF) {
                        float depth = 1.0f / fmaxf(S, EPSF);
                        unsigned long long pk =
                            ((unsigned long long)__float_as_uint(depth) << 32) |
                            (unsigned)sidx[j];
                        if (pk < best) best = pk;
                    }
                }
            }
        }
    }
    dbuf[((size_t)chunk * NB + b) * HW + p] = best;
}

__global__ __launch_bounds__(64) void k_shade(const float* __restrict__ verts,
                                              const int* __restrict__ faces,
                                              const float* __restrict__ vn,
                                              const unsigned long long* __restrict__ dbuf,
                                              float* __restrict__ out) {
    int i = blockIdx.x * 64 + threadIdx.x; // 0..NB*HW-1
    int b = i >> 14;
    int p = i & (HW - 1);
    unsigned long long pk = DINIT;
    for (int k = 0; k < NCHUNK; ++k) {
        unsigned long long v = dbuf[((size_t)k * NB + b) * HW + p];
        if (v < pk) pk = v;
    }
    unsigned dbits = (unsigned)(pk >> 32);
    bool hit = dbits < 0x7F800000u;
    float cr = 255.0f, cg = 255.0f, cb = 255.0f, alpha = 0.0f;
    if (hit) {
        alpha = 1.0f;
        int f = (int)(unsigned)(pk & 0xFFFFFFFFull);
        int row = p >> 7;
        int col = p & 127;
        float px = 1.0f - (2.0f * (float)col + 1.0f) / 128.0f;
        float py = 1.0f - (2.0f * (float)row + 1.0f) / 128.0f;
        int i0 = faces[f * 3 + 0];
        int i1 = faces[f * 3 + 1];
        int i2 = faces[f * 3 + 2];
        const float* wv = verts + (size_t)b * NV * 3;
        float v0x = wv[i0 * 3 + 0], v0y = wv[i0 * 3 + 1], v0z = wv[i0 * 3 + 2];
        float v1x = wv[i1 * 3 + 0], v1y = wv[i1 * 3 + 1], v1z = wv[i1 * 3 + 2];
        float v2x = wv[i2 * 3 + 0], v2y = wv[i2 * 3 + 1], v2z = wv[i2 * 3 + 2];
        // transform, bit-identical to k_face/ref
        float z0 = 2.0f - v0z, z1 = 2.0f - v1z, z2 = 2.0f - v2z;
        float a0x = (12.0f * (-v0x)) / z0, a0y = (12.0f * v0y) / z0;
        float a1x = (12.0f * (-v1x)) / z1, a1y = (12.0f * v1y) / z1;
        float a2x = (12.0f * (-v2x)) / z2, a2y = (12.0f * v2y) / z2;

        float t1 = (a1x - a0x) * (a2y - a0y);
        float t2 = (a1y - a0y) * (a2x - a0x);
        float ar = t1 - t2;
        ar = (fabsf(ar) < EPSF) ? EPSF : ar;
        float u1 = (a2x - a1x) * (py - a1y);
        float u2 = (a2y - a1y) * (px - a1x);
        float bb0 = (u1 - u2) / ar;
        float u3 = (a0x - a2x) * (py - a2y);
        float u4 = (a0y - a2y) * (px - a2x);
        float bb1 = (u3 - u4) / ar;
        float bb2 = (1.0f - bb0) - bb1;
        float w0 = bb0 / z0;
        float w1 = bb1 / z1;
        float w2 = bb2 / z2;
        float denom = ((w0 + w1) + w2) + EPSF;
        float pc0 = w0 / denom;
        float pc1 = w1 / denom;
        float pc2 = w2 / denom;

        float posx = (pc0 * v0x + pc1 * v1x) + pc2 * v2x;
        float posy = (pc0 * v0y + pc1 * v1y) + pc2 * v2y;
        float posz = (pc0 * v0z + pc1 * v1z) + pc2 * v2z;

        const float* vnb = vn + (size_t)b * NV * 3;
        float n0x = vnb[i0 * 3 + 0], n0y = vnb[i0 * 3 + 1], n0z = vnb[i0 * 3 + 2];
        float n1x = vnb[i1 * 3 + 0], n1y = vnb[i1 * 3 + 1], n1z = vnb[i1 * 3 + 2];
        float n2x = vnb[i2 * 3 + 0], n2y = vnb[i2 * 3 + 1], n2z = vnb[i2 * 3 + 2];
        float in0 = 1.0f / (sqrtf(n0x * n0x + n0y * n0y + n0z * n0z) + EPSF);
        float in1 = 1.0f / (sqrtf(n1x * n1x + n1y * n1y + n1z * n1z) + EPSF);
        float in2 = 1.0f / (sqrtf(n2x * n2x + n2y * n2y + n2z * n2z) + EPSF);
        n0x *= in0; n0y *= in0; n0z *= in0;
        n1x *= in1; n1y *= in1; n1z *= in1;
        n2x *= in2; n2y *= in2; n2z *= in2;
        float nx = (pc0 * n0x + pc1 * n1x) + pc2 * n2x;
        float ny = (pc0 * n0y + pc1 * n1y) + pc2 * n2y;
        float nz = (pc0 * n0z + pc1 * n1z) + pc2 * n2z;
        float inn = 1.0f / (sqrtf(nx * nx + ny * ny + nz * nz) + EPSF);
        nx *= inn; ny *= inn; nz *= inn;

        float lx = 0.0f - posx, ly = 1.0f - posy, lz = 3.0f - posz;
        float iln = 1.0f / (sqrtf(lx * lx + ly * ly + lz * lz) + EPSF);
        lx *= iln; ly *= iln; lz *= iln;
        float vx = 0.0f - posx, vy = 0.0f - posy, vz = 2.0f - posz;
        float ivn = 1.0f / (sqrtf(vx * vx + vy * vy + vz * vz) + EPSF);
        vx *= ivn; vy *= ivn; vz *= ivn;

        float ndl = nx * lx + ny * ly + nz * lz;
        float ndlr = fmaxf(ndl, 0.0f);
        float rx = 2.0f * ndl * nx - lx;
        float ry = 2.0f * ndl * ny - ly;
        float rz = 2.0f * ndl * nz - lz;
        float sc = fmaxf(rx * vx + ry * vy + rz * vz, 0.0f);
        float spec = 0.2f * 0.6f * powf(sc, 10.0f);
        float shade = 0.5f * 1.0f + 0.3f * 1.0f * ndlr;
        cr = ((142.0f / 255.0f) * shade + spec) * 255.0f;
        cg = ((179.0f / 255.0f) * shade + spec) * 255.0f;
        cb = ((247.0f / 255.0f) * shade + spec) * 255.0f;
    }
    float* img = out + (size_t)b * 3 * HW;
    img[0 * HW + p] = cr;
    img[1 * HW + p] = cg;
    img[2 * HW + p] = cb;
    out[(size_t)NB * 3 * HW + (size_t)b * HW + p] = alpha;
}

extern "C" void kernel_launch(void* const* d_in, const int* in_sizes, int n_in,
                              void* d_out, int out_size, void* d_ws, size_t ws_size,
                              hipStream_t stream) {
    const float* verts = (const float*)d_in[0]; // [NB, NV, 3]
    const int* faces = (const int*)d_in[1];     // [NF, 3]
    char* ws = (char*)d_ws;
    float* vn = (float*)(ws + 0);
    float4* face = (float4*)(ws + OFF_FACE);
    unsigned long long* dbuf = (unsigned long long*)(ws + OFF_DBUF);
    float* out = (float*)d_out;

    hipMemsetAsync(vn, 0, NB * NV * 3 * sizeof(float), stream);
    k_face<<<(NB * NF + 255) / 256, 256, 0, stream>>>(verts, faces, vn, face);
    k_raster<<<NBLK, 128, 0, stream>>>(face, dbuf);
    k_shade<<<(NB * HW) / 64, 64, 0, stream>>>(verts, faces, vn, dbuf, out);
}